// Round 6
// baseline (252.355 us; speedup 1.0000x reference)
//
#include <hip/hip_runtime.h>

#define B_   16
#define CIN  32
#define COUT 32
#define H_   256
#define W_   256
#define IN_ZP  3
#define OUT_ZP (-5)
#define HW (H_ * W_)
#define TH 8
#define TW 64
#define SW 72   // staged cols: gw = wt-4 .. wt+67
#define SH 10   // staged rows: gh = ht-1 .. ht+8

using i32x4  = __attribute__((ext_vector_type(4))) int;
using i32x16 = __attribute__((ext_vector_type(16))) int;

// ws layout (ints):
//   [0 .. 2303]    B fragments: ws[(t*64+lane)*4+g], byte b =
//                  qweight[co=lane&31][ci=16*(lane>>5)+4g+b][tap t]
//   [2304 .. 2335] shifted bias; [2336..2367] int_scale; [2368..2399] frac_bits
__global__ void qconv_prep(const int* __restrict__ qw, const int* __restrict__ qb,
                           const float* __restrict__ wscale, int* __restrict__ ws) {
    const int co  = blockIdx.x;   // 32 blocks
    const int tid = threadIdx.x;  // 256 threads
    __shared__ int red[4];
    const int* wco = qw + co * (CIN * 9);

    int s = 0;
    for (int i = tid; i < CIN * 9; i += 256) s += wco[i];
    for (int off = 32; off; off >>= 1) s += __shfl_down(s, off, 64);
    if ((tid & 63) == 0) red[tid >> 6] = s;

    if (tid < 72) {
        int gidx = blockIdx.x * 72 + tid;
        int g    = gidx & 3;
        int lane = (gidx >> 2) & 63;
        int t    = gidx >> 8;
        int wco2 = lane & 31;
        int ci0  = 16 * (lane >> 5) + 4 * g;
        const int* base = qw + wco2 * (CIN * 9);
        int b0 = base[(ci0 + 0) * 9 + t] & 0xff;
        int b1 = base[(ci0 + 1) * 9 + t] & 0xff;
        int b2 = base[(ci0 + 2) * 9 + t] & 0xff;
        int b3 = base[(ci0 + 3) * 9 + t] & 0xff;
        ws[gidx] = b0 | (b1 << 8) | (b2 << 16) | (b3 << 24);
    }
    __syncthreads();
    if (tid == 0) {
        int wsum = red[0] + red[1] + red[2] + red[3];
        ws[2304 + co] = qb[co] - wsum * IN_ZP;
        float fs = (0.02f * wscale[co]) / 0.05f;
        float fb = floorf(log2f(127.0f / fs));
        ws[2336 + co] = (int)rintf(fs * exp2f(fb));  // half-to-even, matches jnp.round
        ws[2368 + co] = (int)fb;
    }
}

// branch-free staging of one packed item (clamped loads + select for pad)
__device__ __forceinline__ void stage_item(int idx, int ht, int wt,
                                           const int* __restrict__ xb,
                                           int (*smem)[SH][SW]) {
    int cig = idx / 180;
    int rem = idx - cig * 180;
    int r   = rem / 18;
    int c4  = rem - r * 18;
    int gh  = ht - 1 + r;
    int gw0 = wt - 4 + c4 * 4;
    int ghc = min(H_ - 1, max(0, gh));
    int gwc = min(W_ - 4, max(0, gw0));
    const int* p = xb + (cig * 4) * HW + ghc * W_ + gwc;
    i32x4 v0 = *(const i32x4*)(p);
    i32x4 v1 = *(const i32x4*)(p + HW);
    i32x4 v2 = *(const i32x4*)(p + 2 * HW);
    i32x4 v3 = *(const i32x4*)(p + 3 * HW);
    bool vh = (unsigned)gh < (unsigned)H_;
    i32x4 pk;
#pragma unroll
    for (int j = 0; j < 4; ++j) {
        int t = (v0[j] & 0xff) | ((v1[j] & 0xff) << 8) |
                ((v2[j] & 0xff) << 16) | (v3[j] << 24);
        bool ok = vh && ((unsigned)(gw0 + j) < (unsigned)W_);
        pk[j] = ok ? t : 0x03030303;
    }
    *(i32x4*)&smem[cig][r][c4 * 4] = pk;
}

__global__ __launch_bounds__(256) void qconv_fused(const int* __restrict__ x,
                                                   const int* __restrict__ ws,
                                                   int* __restrict__ out) {
    __shared__ int smem[8][SH][SW];  // packed int8x4 im2col tile (23 KB only)
    const int wt = blockIdx.x * TW;
    const int ht = blockIdx.y * TH;
    const int b  = blockIdx.z;
    const int tid = threadIdx.x;
    const int* xb = x + b * (CIN * HW);

    // ---- staging: 1440 items, 6 per thread, straight-line & branch-free ----
    stage_item(tid,        ht, wt, xb, smem);
    stage_item(tid + 256,  ht, wt, xb, smem);
    stage_item(tid + 512,  ht, wt, xb, smem);
    stage_item(tid + 768,  ht, wt, xb, smem);
    stage_item(tid + 1024, ht, wt, xb, smem);
    if (tid < 160) stage_item(tid + 1280, ht, wt, xb, smem);
    __syncthreads();

    const int lane = tid & 63, wv = tid >> 6;
    const int co = lane & 31, hh = lane >> 5;

    i32x4 bfrag[9];
    const i32x4* bws = (const i32x4*)ws;
#pragma unroll
    for (int t = 0; t < 9; ++t) bfrag[t] = bws[t * 64 + lane];

    const int sb  = ws[2304 + co];
    const int isc = ws[2336 + co];
    const int fb  = ws[2368 + co];

    // 16 M-tiles (8 rows x 2 col-chunks of 32); 4 per wave; direct C-layout stores
#pragma unroll
    for (int i = 0; i < 4; ++i) {
        int mt = wv * 4 + i;
        int r0 = mt >> 1, chunk = mt & 1;
        i32x16 acc;
#pragma unroll
        for (int r = 0; r < 16; ++r) acc[r] = sb;
#pragma unroll
        for (int t = 0; t < 9; ++t) {
            int dh = t / 3, dw = t % 3;
            int rr = r0 + dh;
            int c  = chunk * 32 + (lane & 31) + dw + 3;
            i32x4 a;
#pragma unroll
            for (int g = 0; g < 4; ++g) a[g] = smem[4 * hh + g][rr][c];
            acc = __builtin_amdgcn_mfma_i32_32x32x32_i8(a, bfrag[t], acc, 0, 0, 0);
        }
        int* op = out + (b * COUT + co) * HW + (ht + r0) * W_ + wt + chunk * 32 + 4 * hh;
#pragma unroll
        for (int rg = 0; rg < 4; ++rg) {
            i32x4 v;
#pragma unroll
            for (int j = 0; j < 4; ++j) {
                int t2 = (int)((unsigned)acc[rg * 4 + j] * (unsigned)isc) >> fb;
                t2 += OUT_ZP;
                v[j] = min(127, max(-128, t2));
            }
            *(i32x4*)(op + 8 * rg) = v;
        }
    }
}

extern "C" void kernel_launch(void* const* d_in, const int* in_sizes, int n_in,
                              void* d_out, int out_size, void* d_ws, size_t ws_size,
                              hipStream_t stream) {
    const int*   x   = (const int*)d_in[0];
    const int*   qw  = (const int*)d_in[1];
    const int*   qb  = (const int*)d_in[2];
    const float* wsc = (const float*)d_in[3];
    int* ws  = (int*)d_ws;
    int* out = (int*)d_out;

    qconv_prep<<<32, 256, 0, stream>>>(qw, qb, wsc, ws);
    dim3 grid(W_ / TW, H_ / TH, B_);
    qconv_fused<<<grid, 256, 0, stream>>>(x, ws, out);
}